// Round 10
// baseline (296.361 us; speedup 1.0000x reference)
//
#include <hip/hip_runtime.h>
#include <math.h>

#define DEV static __device__ __forceinline__

typedef float v2 __attribute__((ext_vector_type(2)));

// Quad-perm DPP — full-rate VALU, 1-2 cyc forwarding. ALL cross-lane traffic
// in this layout is quad-local (lane bits 0-1 = qubits n2,n3), so no LDS pipe
// and no ds_swizzle latency anywhere.
template<int CTRL>
DEV float qperm(float x) {
    return __int_as_float(__builtin_amdgcn_mov_dpp(__float_as_int(x), CTRL, 0xF, 0xF, true));
}
DEV float lx1(float v)  { return qperm<0xB1>(v); }   // xor lane bit0 (n2)
DEV float lx2(float v)  { return qperm<0x4E>(v); }   // xor lane bit1 (n3)
DEV float x3f_(float v) { return qperm<0x1B>(v); }   // xor both (n2,n3)
DEV float rfl(float x)  { return __int_as_float(__builtin_amdgcn_readfirstlane(__float_as_int(x))); }

DEV v2 lx1v(v2 a) { return (v2){lx1(a.x), lx1(a.y)}; }
DEV v2 lx2v(v2 a) { return (v2){lx2(a.x), lx2(a.y)}; }
DEV v2 x3v(v2 a)  { return (v2){x3f_(a.x), x3f_(a.y)}; }

// masked-rot update with SCALAR complex coefficients:
//   n = (dr + i*di) * A + (orr + i*oi) * P     (sign variants via free VOP3 negs)
DEV v2 gup_s(v2 A, v2 P, float dr, float di, float orr, float oi) {
    v2 n;
    n.x = A.x*dr; n.x = fmaf(A.y, -di, n.x); n.x = fmaf(P.x, orr, n.x); n.x = fmaf(P.y, -oi, n.x);
    n.y = A.y*dr; n.y = fmaf(A.x,  di, n.y); n.y = fmaf(P.y, orr, n.y); n.y = fmaf(P.x,  oi, n.y);
    return n;
}
// diagonal phase: A *= (c + i*s), pair packed as {c,s}
DEV v2 prot(v2 A, v2 cs) {
    v2 n;
    n.x = A.x*cs.x; n.x = fmaf(A.y, -cs.y, n.x);
    n.y = A.y*cs.x; n.y = fmaf(A.x,  cs.y, n.y);
    return n;
}

// Cheap sincos in REVOLUTIONS: v_fract + v_sin + v_cos.
DEV void fsincos(float rev, float* s, float* c) {
    float f = __builtin_amdgcn_fractf(rev);
    *s = __builtin_amdgcn_sinf(f);
    *c = __builtin_amdgcn_cosf(f);
}

__global__ __launch_bounds__(256, 1)
void qrnn_kernel(const float* __restrict__ inputs, const float* __restrict__ initial_t,
                 const float* __restrict__ p1, const float* __restrict__ p2,
                 const float* __restrict__ kbw, const float* __restrict__ ksw,
                 const float* __restrict__ w1, const float* __restrict__ cb1,
                 const float* __restrict__ w2, const float* __restrict__ cb2,
                 float* __restrict__ out, int B, int S)
{
    // 4-lane layout: lane bit0->n2, bit1->n3; n0,n1 live IN REGISTERS:
    // each thread holds a[n0][n1] (4 complex amps). 4 lanes = 1 element,
    // wave = 16 elements. B*4 threads -> 256 blocks -> 1 wave/SIMD.
    // Phase_x trig is SOFTWARE-PIPELINED ACROSS THE BACK-EDGE: PC(t+1) is
    // computed right after measurement(t), inside the serial KAN window —
    // the only independent work that can fill that loop-carried chain
    // (the compiler cannot hoist it across the back-edge itself).
    const int tid = blockIdx.x * blockDim.x + threadIdx.x;
    const int e   = tid >> 2;
    if (e >= B) return;
    const int sub = threadIdx.x & 3;
    const bool b2 = (sub & 1) != 0, b3 = (sub & 2) != 0;
    const float z2f = b2 ? -1.f : 1.f;
    const float z3f = b3 ? -1.f : 1.f;
    const float z23 = z2f * z3f;
    const bool is0 = (sub == 0), is1 = (sub == 1), is2 = (sub == 2);

    // Angles in REVOLUTIONS with -0.5 half-angle folded: stored = -rad/(4*pi).
    const float REVC = -0.07957747154594767f;   // -1/(4*pi)
    const float NQPI = -0.7853981633974483f;    // -pi/4

    // ---- one-time: 16 base Rot matrices (input-constant)
    float u00r[4][4], u00i[4][4], u01r[4][4], u01i[4][4];
    const float* PP[2] = { p1, p2 };
#pragma unroll
    for (int aI = 0; aI < 2; ++aI) {
        const float* pp = PP[aI];
#pragma unroll
        for (int l = 0; l < 2; ++l) {
            const int idx = aI*2 + l;
#pragma unroll
            for (int q = 0; q < 4; ++q) {
                float phi = pp[l*12 + q*3 + 0];
                float tht = pp[l*12 + q*3 + 1];
                float omg = pp[l*12 + q*3 + 2];
                float st, ct; sincosf(0.5f*tht, &st, &ct);
                float sA, cA, sB, cB;
                sincosf(0.5f*(phi + omg), &sA, &cA);
                sincosf(0.5f*(phi - omg), &sB, &cB);
                u00r[idx][q] = rfl( cA*ct); u00i[idx][q] = rfl(-sA*ct);
                u01r[idx][q] = rfl(-cB*st); u01i[idx][q] = rfl(-sB*st);
            }
        }
    }

    // ---- per-gate scalar coefficients {dr, di, orr, oi}, z2/z3 parts folded.
    // gates 0-3: L0 q0..q3; 4-7: L1' g0..g3 (det-1, sigma on dr&oi);
    // 8-11: L2 g0..g3 (det+1, sigma on di&orr); 12-15: L3 g0..g3.
    // Chain-sign (eps0/eps1) parts applied at call sites via negation.
    float cdr[16], cdi[16], cor_[16], coi[16];
    {
        const float f0[4] = {1.f, 1.f, z2f, z3f};          // L0 sigma: n0, n1, z2, z3
#pragma unroll
        for (int q = 0; q < 4; ++q) {
            cdr[q]  = u00r[0][q];
            cdi[q]  = f0[q]*u00i[0][q];
            cor_[q] = f0[q]*u01r[0][q];
            coi[q]  = u01i[0][q];
        }
        const float f1a[4] = {z23, 1.f, z2f, z23};         // L1' sigma z-parts
#pragma unroll
        for (int q = 0; q < 4; ++q) {
            float ar = u00r[1][q] - u01r[1][q];
            float ai = u00i[1][q] + u01i[1][q];
            float br = u00r[1][q] + u01r[1][q];
            float bi = u01i[1][q] - u00i[1][q];
            cdr[4+q]  = f1a[q]*ar;
            cdi[4+q]  = ai;
            cor_[4+q] = br;
            coi[4+q]  = f1a[q]*bi;
        }
        const float f2a[4] = {z23, z2f, z3f, 1.f};         // L2 sigma z-parts
#pragma unroll
        for (int q = 0; q < 4; ++q) {
            cdr[8+q]  = u00r[2][q];
            cdi[8+q]  = f2a[q]*u00i[2][q];
            cor_[8+q] = f2a[q]*u01r[2][q];
            coi[8+q]  = u01i[2][q];
        }
        const float f3a[4] = {z23, z3f, 1.f, 1.f};         // L3 sigma z-parts
#pragma unroll
        for (int q = 0; q < 4; ++q) {
            cdr[12+q]  = u00r[3][q];
            cdi[12+q]  = f3a[q]*u00i[3][q];
            cor_[12+q] = f3a[q]*u01r[3][q];
            coi[12+q]  = u01i[3][q];
        }
    }

    // ---- KAN cubic coeffs (lane 'sub' = input dim); REVC folded.
    float kQ0[7], kQ1[7], kQ2[7], kQ3[7], kBW[7];
#pragma unroll
    for (int r = 0; r < 7; ++r) {
        float sw0 = ksw[r*16 + sub*4 + 0], sw1 = ksw[r*16 + sub*4 + 1];
        float sw2 = ksw[r*16 + sub*4 + 2], sw3 = ksw[r*16 + sub*4 + 3];
        const float f = REVC / 48.0f;
        kQ0[r] = f * (sw0 + 23.f*sw1 + 23.f*sw2 + sw3);
        kQ1[r] = f * (-3.f*sw0 - 15.f*sw1 + 15.f*sw2 + 3.f*sw3);
        kQ2[r] = f * (3.f*sw0 - 3.f*sw1 - 3.f*sw2 + 3.f*sw3);
        kQ3[r] = f * (-sw0 + 3.f*sw1 - 3.f*sw2 + sw3);
        kBW[r] = REVC * kbw[r*4 + sub];
    }
    const int pr0[3] = {0, 1, 3}, pr1[3] = {4, 2, 6};
    v2 Q0p[3], Q1p[3], Q2p[3], Q3p[3], BWp[3];
#pragma unroll
    for (int j = 0; j < 3; ++j) {
        Q0p[j] = (v2){kQ0[pr0[j]], kQ0[pr1[j]]};
        Q1p[j] = (v2){kQ1[pr0[j]], kQ1[pr1[j]]};
        Q2p[j] = (v2){kQ2[pr0[j]], kQ2[pr1[j]]};
        Q3p[j] = (v2){kQ3[pr0[j]], kQ3[pr1[j]]};
        BWp[j] = (v2){kBW[pr0[j]], kBW[pr1[j]]};
    }

    // measurement residual sign + /256
    const float SCL = (is0 ? z3f : z2f) * (1.0f/256.0f);
    const float zNQ3  = z3f * NQPI;
    const float zNQ23 = z23 * NQPI;

    // phase_x from input vector X -> per-chain {cos,sin}
    auto phase_calc = [&](float4 X, v2& o00, v2& o01, v2& o10, v2& o11) {
        float hx0 = REVC*X.x, hx1 = REVC*X.y;
        float hx2 = REVC*X.z, hx3 = REVC*X.w;
        float u0 = fmaf(4.f, hx0, 1.f);
        float u1 = fmaf(4.f, hx1, 1.f);
        float u2 = fmaf(4.f, hx2, 1.f);
        float u3 = fmaf(4.f, hx3, 1.f);
        float h4r = u0*u1, h5r = u1*u2, h6r = u2*u3;
        float c2 = z2f*hx1;
        c2 = fmaf(z3f, hx2, c2);
        c2 = fmaf(zNQ23, h5r, c2);
        float d2 = fmaf(zNQ3, h6r, hx3);
        float w2 = fmaf(zNQ3, h4r, z23*hx0);
        float p2 = c2 + d2, q2v = c2 - d2;
        float ps, pc, qs, qc, rs, rc, ss_, sc;
        fsincos(p2 + w2,  &ps, &pc);
        fsincos(q2v + w2, &qs, &qc);
        fsincos(p2 - w2,  &rs, &rc);
        fsincos(q2v - w2, &ss_, &sc);
        o00 = (v2){pc, ps}; o01 = (v2){qc, qs};
        o10 = (v2){rc, rs}; o11 = (v2){sc, ss_};
    };

    // ---- per-element state
    v2 H04, H12, H36;
    float H5;
    const float4* inp4 = (const float4*)inputs;
    H04 = (v2){REVC*initial_t[e*7+0], REVC*initial_t[e*7+4]};
    H12 = (v2){REVC*initial_t[e*7+1], REVC*initial_t[e*7+2]};
    H36 = (v2){REVC*initial_t[e*7+3], REVC*initial_t[e*7+6]};
    H5  = REVC*initial_t[e*7+5];
    const long BASE = (long)e * S;

    float XK = 0.f;
    v2 a00, a01, a10, a11;   // a[n0][n1]

    // ---- prologue: PC(0) from x_0
    v2 pcc00, pcc01, pcc10, pcc11;
    phase_calc(inp4[BASE], pcc00, pcc01, pcc10, pcc11);

#pragma unroll 1
    for (int t = 0; t < S; ++t) {
        const int tn = (t + 1 < S) ? t + 1 : S - 1;
        float4 XN = inp4[BASE + tn];

        // ---- fm(hidden) on |0000>: sig(a,b) = c + e1*d + e0*(w0 + e1*w1)
        {
            float c_ = z2f*H12.y;
            c_ = fmaf(z3f, H36.x, c_);
            c_ = fmaf(z23, H36.y, c_);
            float d_ = fmaf(z2f, H5, H12.x);
            float w0 = H04.x, w1 = H04.y;
            float pd = c_ + d_, qd = c_ - d_;
            float rw = w0 + w1, sw = w0 - w1;
            float s00,c00,s01,c01,s10,c10,s11,c11;
            fsincos(pd + rw, &s00, &c00);
            fsincos(qd + sw, &s01, &c01);
            fsincos(pd - rw, &s10, &c10);
            fsincos(qd - sw, &s11, &c11);
            a00 = (v2){c00, s00}; a01 = (v2){c01, s01};
            a10 = (v2){c10, s10}; a11 = (v2){c11, s11};
        }

        // ======== L0: ansatz1 layer1 ========
        {   // q0: n0-pair; eps0 on (di,orr)
            v2 n00 = gup_s(a00, a10, cdr[0],  cdi[0],  cor_[0], coi[0]);
            v2 n10 = gup_s(a10, a00, cdr[0], -cdi[0], -cor_[0], coi[0]);
            v2 n01 = gup_s(a01, a11, cdr[0],  cdi[0],  cor_[0], coi[0]);
            v2 n11 = gup_s(a11, a01, cdr[0], -cdi[0], -cor_[0], coi[0]);
            a00=n00; a10=n10; a01=n01; a11=n11;
        }
        {   // q1: n1-pair; eps1 on (di,orr)
            v2 n00 = gup_s(a00, a01, cdr[1],  cdi[1],  cor_[1], coi[1]);
            v2 n01 = gup_s(a01, a00, cdr[1], -cdi[1], -cor_[1], coi[1]);
            v2 n10 = gup_s(a10, a11, cdr[1],  cdi[1],  cor_[1], coi[1]);
            v2 n11 = gup_s(a11, a10, cdr[1], -cdi[1], -cor_[1], coi[1]);
            a00=n00; a01=n01; a10=n10; a11=n11;
        }
        // q2: lx1 self; z2 in consts
        a00 = gup_s(a00, lx1v(a00), cdr[2], cdi[2], cor_[2], coi[2]);
        a01 = gup_s(a01, lx1v(a01), cdr[2], cdi[2], cor_[2], coi[2]);
        a10 = gup_s(a10, lx1v(a10), cdr[2], cdi[2], cor_[2], coi[2]);
        a11 = gup_s(a11, lx1v(a11), cdr[2], cdi[2], cor_[2], coi[2]);
        // q3: lx2 self; z3 in consts
        a00 = gup_s(a00, lx2v(a00), cdr[3], cdi[3], cor_[3], coi[3]);
        a01 = gup_s(a01, lx2v(a01), cdr[3], cdi[3], cor_[3], coi[3]);
        a10 = gup_s(a10, lx2v(a10), cdr[3], cdi[3], cor_[3], coi[3]);
        a11 = gup_s(a11, lx2v(a11), cdr[3], cdi[3], cor_[3], coi[3]);

        // ======== L1': H-folded ansatz1 layer2 (det -1; sigma on dr&oi) ========
        {   // g0: mask {n0,n1}: cross-pair; eps1 on (dr,oi)
            v2 n00 = gup_s(a00, a11,  cdr[4], cdi[4], cor_[4],  coi[4]);
            v2 n01 = gup_s(a01, a10, -cdr[4], cdi[4], cor_[4], -coi[4]);
            v2 n10 = gup_s(a10, a01,  cdr[4], cdi[4], cor_[4],  coi[4]);
            v2 n11 = gup_s(a11, a00, -cdr[4], cdi[4], cor_[4], -coi[4]);
            a00=n00; a01=n01; a10=n10; a11=n11;
        }
        {   // g1: mask {n1,n2}: n1-pair + lx1; eps0*eps1 on (dr,oi)
            v2 p00 = lx1v(a01), p01 = lx1v(a00), p10 = lx1v(a11), p11 = lx1v(a10);
            v2 n00 = gup_s(a00, p00,  cdr[5], cdi[5], cor_[5],  coi[5]);
            v2 n01 = gup_s(a01, p01, -cdr[5], cdi[5], cor_[5], -coi[5]);
            v2 n10 = gup_s(a10, p10, -cdr[5], cdi[5], cor_[5], -coi[5]);
            v2 n11 = gup_s(a11, p11,  cdr[5], cdi[5], cor_[5],  coi[5]);
            a00=n00; a01=n01; a10=n10; a11=n11;
        }
        // g2: mask {n2,n3}: x3 self; eps0*eps1 on (dr,oi)
        a00 = gup_s(a00, x3v(a00),  cdr[6], cdi[6], cor_[6],  coi[6]);
        a01 = gup_s(a01, x3v(a01), -cdr[6], cdi[6], cor_[6], -coi[6]);
        a10 = gup_s(a10, x3v(a10), -cdr[6], cdi[6], cor_[6], -coi[6]);
        a11 = gup_s(a11, x3v(a11),  cdr[6], cdi[6], cor_[6],  coi[6]);
        {   // g3: mask {n0,n1,n3}: cross-pair + lx2; eps0*eps1 on (dr,oi)
            v2 p00 = lx2v(a11), p01 = lx2v(a10), p10 = lx2v(a01), p11 = lx2v(a00);
            v2 n00 = gup_s(a00, p00,  cdr[7], cdi[7], cor_[7],  coi[7]);
            v2 n01 = gup_s(a01, p01, -cdr[7], cdi[7], cor_[7], -coi[7]);
            v2 n10 = gup_s(a10, p10, -cdr[7], cdi[7], cor_[7], -coi[7]);
            v2 n11 = gup_s(a11, p11,  cdr[7], cdi[7], cor_[7],  coi[7]);
            a00=n00; a01=n01; a10=n10; a11=n11;
        }

        // ======== Phase_x apply (PC computed in PREVIOUS iteration) ========
        a00 = prot(a00, pcc00);
        a01 = prot(a01, pcc01);
        a10 = prot(a10, pcc10);
        a11 = prot(a11, pcc11);

        // ======== L2: ansatz2 layer1 (det +1; sigma on di&orr) ========
        {   // g0: mask {n0}: n0-pair; eps0 on (di,orr)
            v2 n00 = gup_s(a00, a10, cdr[8],  cdi[8],  cor_[8], coi[8]);
            v2 n10 = gup_s(a10, a00, cdr[8], -cdi[8], -cor_[8], coi[8]);
            v2 n01 = gup_s(a01, a11, cdr[8],  cdi[8],  cor_[8], coi[8]);
            v2 n11 = gup_s(a11, a01, cdr[8], -cdi[8], -cor_[8], coi[8]);
            a00=n00; a10=n10; a01=n01; a11=n11;
        }
        {   // g1: mask {n0,n2}: n0-pair + lx1; no chain signs (z2 in consts)
            v2 p00 = lx1v(a10), p10 = lx1v(a00), p01 = lx1v(a11), p11 = lx1v(a01);
            v2 n00 = gup_s(a00, p00, cdr[9], cdi[9], cor_[9], coi[9]);
            v2 n10 = gup_s(a10, p10, cdr[9], cdi[9], cor_[9], coi[9]);
            v2 n01 = gup_s(a01, p01, cdr[9], cdi[9], cor_[9], coi[9]);
            v2 n11 = gup_s(a11, p11, cdr[9], cdi[9], cor_[9], coi[9]);
            a00=n00; a10=n10; a01=n01; a11=n11;
        }
        {   // g2: mask {n0,n3}: n0-pair + lx2; no chain signs (z3 in consts)
            v2 p00 = lx2v(a10), p10 = lx2v(a00), p01 = lx2v(a11), p11 = lx2v(a01);
            v2 n00 = gup_s(a00, p00, cdr[10], cdi[10], cor_[10], coi[10]);
            v2 n10 = gup_s(a10, p10, cdr[10], cdi[10], cor_[10], coi[10]);
            v2 n01 = gup_s(a01, p01, cdr[10], cdi[10], cor_[10], coi[10]);
            v2 n11 = gup_s(a11, p11, cdr[10], cdi[10], cor_[10], coi[10]);
            a00=n00; a10=n10; a01=n01; a11=n11;
        }
        {   // g3: mask {n1}: n1-pair; eps1 on (di,orr)
            v2 n00 = gup_s(a00, a01, cdr[11],  cdi[11],  cor_[11], coi[11]);
            v2 n01 = gup_s(a01, a00, cdr[11], -cdi[11], -cor_[11], coi[11]);
            v2 n10 = gup_s(a10, a11, cdr[11],  cdi[11],  cor_[11], coi[11]);
            v2 n11 = gup_s(a11, a10, cdr[11], -cdi[11], -cor_[11], coi[11]);
            a00=n00; a01=n01; a10=n10; a11=n11;
        }

        // ======== L3: ansatz2 layer2 (det +1; sigma on di&orr) ========
        // g0: mask {n2}: lx1 self; eps1 on (di,orr), z23 in consts
        a00 = gup_s(a00, lx1v(a00), cdr[12],  cdi[12],  cor_[12], coi[12]);
        a01 = gup_s(a01, lx1v(a01), cdr[12], -cdi[12], -cor_[12], coi[12]);
        a10 = gup_s(a10, lx1v(a10), cdr[12],  cdi[12],  cor_[12], coi[12]);
        a11 = gup_s(a11, lx1v(a11), cdr[12], -cdi[12], -cor_[12], coi[12]);
        // g1: mask {n2,n3}: x3 self; eps0 on (di,orr), z3 in consts
        a00 = gup_s(a00, x3v(a00), cdr[13],  cdi[13],  cor_[13], coi[13]);
        a01 = gup_s(a01, x3v(a01), cdr[13],  cdi[13],  cor_[13], coi[13]);
        a10 = gup_s(a10, x3v(a10), cdr[13], -cdi[13], -cor_[13], coi[13]);
        a11 = gup_s(a11, x3v(a11), cdr[13], -cdi[13], -cor_[13], coi[13]);
        {   // g2: mask {n0,n1,n3}: cross-pair + lx2; eps0 on (di,orr)
            v2 p00 = lx2v(a11), p01 = lx2v(a10), p10 = lx2v(a01), p11 = lx2v(a00);
            v2 n00 = gup_s(a00, p00, cdr[14],  cdi[14],  cor_[14], coi[14]);
            v2 n01 = gup_s(a01, p01, cdr[14],  cdi[14],  cor_[14], coi[14]);
            v2 n10 = gup_s(a10, p10, cdr[14], -cdi[14], -cor_[14], coi[14]);
            v2 n11 = gup_s(a11, p11, cdr[14], -cdi[14], -cor_[14], coi[14]);
            a00=n00; a01=n01; a10=n10; a11=n11;
        }
        {   // g3: mask {n1,n2}: n1-pair + lx1; eps0*eps1 on (di,orr)
            v2 p00 = lx1v(a01), p01 = lx1v(a00), p10 = lx1v(a11), p11 = lx1v(a10);
            v2 n00 = gup_s(a00, p00, cdr[15],  cdi[15],  cor_[15], coi[15]);
            v2 n01 = gup_s(a01, p01, cdr[15], -cdi[15], -cor_[15], coi[15]);
            v2 n10 = gup_s(a10, p10, cdr[15], -cdi[15], -cor_[15], coi[15]);
            v2 n11 = gup_s(a11, p11, cdr[15],  cdi[15],  cor_[15], coi[15]);
            a00=n00; a01=n01; a10=n10; a11=n11;
        }

        // ---- measurement (Walsh over n0,n1 in-register; n2,n3 quad DPP)
        // EV0 = sum(-1)^{n0+n1+n3}p, EV1 = sum(-1)^{n0+n1+n2}p,
        // EV2 = sum(-1)^{n1+n2}p,    EV3 = sum(-1)^{n0+n2}p   (probs x256)
        {
            float m00 = fmaf(a00.y, a00.y, a00.x*a00.x);
            float m01 = fmaf(a01.y, a01.y, a01.x*a01.x);
            float m10 = fmaf(a10.y, a10.y, a10.x*a10.x);
            float m11 = fmaf(a11.y, a11.y, a11.x*a11.x);
            float g_ = m00 - m01, h_ = m10 - m11;
            float dl01 = g_ - h_;                         // (-1)^{n0^n1}
            float sn1  = g_ + h_;                         // (-1)^{n1}
            float dn0  = (m00 + m01) - (m10 + m11);       // (-1)^{n0}
            float l1a = lx1(dl01);
            float up = dl01 + l1a;
            float um = dl01 - l1a;
            float t0 = up - lx2(up);                      // z3f * EV0*256
            float t1 = um + lx2(um);                      // z2f * EV1*256
            float vm = sn1 - lx1(sn1);
            float t2 = vm + lx2(vm);                      // z2f * EV2*256
            float wm = dn0 - lx1(dn0);
            float t3 = wm + lx2(wm);                      // z2f * EV3*256
            float pre = is0 ? t0 : (is1 ? t1 : (is2 ? t2 : t3));
            XK = pre * SCL;
        }

        // ---- PIPELINED: PC(t+1) from XN — fills the serial KAN window below
        v2 pcn00, pcn01, pcn10, pcn11;
        phase_calc(XN, pcn00, pcn01, pcn10, pcn11);

        // ---- KAN (packed pairs): lane sub = input dim; quad-reduce sums dims
        {
            float xk = XK;
            float eneg = __builtin_amdgcn_exp2f(xk * -1.44269504088896f);
            float silu = xk * __builtin_amdgcn_rcpf(1.0f + eneg);
            v2 xs = (v2){xk, xk}, ss = (v2){silu, silu};
            v2 op[3];
#pragma unroll
            for (int k = 0; k < 3; ++k) {
                v2 o = __builtin_elementwise_fma(Q3p[k], xs, Q2p[k]);
                o = __builtin_elementwise_fma(o, xs, Q1p[k]);
                o = __builtin_elementwise_fma(o, xs, Q0p[k]);
                o = __builtin_elementwise_fma(BWp[k], ss, o);
                o = o + (v2){lx1(o.x), lx1(o.y)};
                o = o + (v2){lx2(o.x), lx2(o.y)};
                op[k] = o;
            }
            {   // scalar r=5
                float o = fmaf(kQ3[5], xk, kQ2[5]);
                o = fmaf(o, xk, kQ1[5]);
                o = fmaf(o, xk, kQ0[5]);
                o = fmaf(kBW[5], silu, o);
                o += lx1(o); o += lx2(o);
                H5 = o;
            }
            H04 = op[0]; H12 = op[1]; H36 = op[2];
        }

        // rotate pipeline registers
        pcc00 = pcn00; pcc01 = pcn01; pcc10 = pcn10; pcc11 = pcn11;
    }

    // ---- classifier head: quad lanes hold ev0..ev3 per element
    {
        float xk  = XK;
        float ev1 = qperm<0x55>(xk);
        float ev2 = qperm<0xAA>(xk);
        float ev3 = qperm<0xFF>(xk);
        if (is0) {
            float acc = cb2[0];
#pragma unroll
            for (int i = 0; i < 16; ++i) {
                float h = cb1[i] + w1[i*4+0]*xk + w1[i*4+1]*ev1
                        + w1[i*4+2]*ev2 + w1[i*4+3]*ev3;
                h = fmaxf(h, 0.0f);
                acc += w2[i]*h;
            }
            out[e] = acc;
        }
    }
}

extern "C" void kernel_launch(void* const* d_in, const int* in_sizes, int n_in,
                              void* d_out, int out_size, void* d_ws, size_t ws_size,
                              hipStream_t stream) {
    const float* inputs    = (const float*)d_in[0];
    const float* initial_t = (const float*)d_in[1];
    const float* p1        = (const float*)d_in[2];
    const float* p2        = (const float*)d_in[3];
    const float* kbw       = (const float*)d_in[4];
    const float* ksw       = (const float*)d_in[5];
    const float* w1        = (const float*)d_in[6];
    const float* cb1       = (const float*)d_in[7];
    const float* w2        = (const float*)d_in[8];
    const float* cb2       = (const float*)d_in[9];

    const int B = in_sizes[1] / 7;            // 16384
    const int S = in_sizes[0] / (B * 4);      // 256

    const int threads = B * 4;                // 4 lanes/element, 1 element/thread
    const int block = 256;
    const int grid = (threads + block - 1) / block;   // 256 blocks -> 1 wave/SIMD

    qrnn_kernel<<<grid, block, 0, stream>>>(inputs, initial_t, p1, p2, kbw, ksw,
                                            w1, cb1, w2, cb2, (float*)d_out, B, S);
}

// Round 11
// 281.510 us; speedup vs baseline: 1.0528x; 1.0528x over previous
//
#include <hip/hip_runtime.h>
#include <math.h>

#define DEV static __device__ __forceinline__

typedef float v2 __attribute__((ext_vector_type(2)));

// Quad-perm DPP — full-rate VALU, 1-2 cyc forwarding. ALL cross-lane traffic
// in this layout is quad-local (lane bits 0-1 = qubits n2,n3), so no LDS pipe
// and no ds_swizzle latency anywhere.
template<int CTRL>
DEV float qperm(float x) {
    return __int_as_float(__builtin_amdgcn_mov_dpp(__float_as_int(x), CTRL, 0xF, 0xF, true));
}
DEV float lx1(float v)  { return qperm<0xB1>(v); }   // xor lane bit0 (n2)
DEV float lx2(float v)  { return qperm<0x4E>(v); }   // xor lane bit1 (n3)
DEV float x3f_(float v) { return qperm<0x1B>(v); }   // xor both (n2,n3)
DEV float rfl(float x)  { return __int_as_float(__builtin_amdgcn_readfirstlane(__float_as_int(x))); }

DEV v2 lx1v(v2 a) { return (v2){lx1(a.x), lx1(a.y)}; }
DEV v2 lx2v(v2 a) { return (v2){lx2(a.x), lx2(a.y)}; }
DEV v2 x3v(v2 a)  { return (v2){x3f_(a.x), x3f_(a.y)}; }

// masked-rot update with SCALAR complex coefficients:
//   n = (dr + i*di) * A + (orr + i*oi) * P     (sign variants via free VOP3 negs)
DEV v2 gup_s(v2 A, v2 P, float dr, float di, float orr, float oi) {
    v2 n;
    n.x = A.x*dr; n.x = fmaf(A.y, -di, n.x); n.x = fmaf(P.x, orr, n.x); n.x = fmaf(P.y, -oi, n.x);
    n.y = A.y*dr; n.y = fmaf(A.x,  di, n.y); n.y = fmaf(P.y, orr, n.y); n.y = fmaf(P.x,  oi, n.y);
    return n;
}
// diagonal phase: A *= (c + i*s), pair packed as {c,s}
DEV v2 prot(v2 A, v2 cs) {
    v2 n;
    n.x = A.x*cs.x; n.x = fmaf(A.y, -cs.y, n.x);
    n.y = A.y*cs.x; n.y = fmaf(A.x,  cs.y, n.y);
    return n;
}

// Cheap sincos in REVOLUTIONS: v_fract + v_sin + v_cos.
DEV void fsincos(float rev, float* s, float* c) {
    float f = __builtin_amdgcn_fractf(rev);
    *s = __builtin_amdgcn_sinf(f);
    *c = __builtin_amdgcn_cosf(f);
}

__global__ __launch_bounds__(256, 1)
void qrnn_kernel(const float* __restrict__ inputs, const float* __restrict__ initial_t,
                 const float* __restrict__ p1, const float* __restrict__ p2,
                 const float* __restrict__ kbw, const float* __restrict__ ksw,
                 const float* __restrict__ w1, const float* __restrict__ cb1,
                 const float* __restrict__ w2, const float* __restrict__ cb2,
                 float* __restrict__ out, int B, int S)
{
    // 4-lane layout: lane bit0->n2, bit1->n3; n0,n1 live IN REGISTERS:
    // each thread holds a[n0][n1] (4 complex amps). 4 lanes = 1 element,
    // wave = 16 elements. B*4 threads -> 256 blocks -> 1 wave/SIMD (grid-
    // structural; more TLP impossible without raising demand).
    // Phase_x trig depends only on XC and has no in-iteration consumers
    // until after L1' — the compiler schedules it freely (R8 proved that
    // constraining its position only hurts).
    const int tid = blockIdx.x * blockDim.x + threadIdx.x;
    const int e   = tid >> 2;
    if (e >= B) return;
    const int sub = threadIdx.x & 3;
    const bool b2 = (sub & 1) != 0, b3 = (sub & 2) != 0;
    const float z2f = b2 ? -1.f : 1.f;
    const float z3f = b3 ? -1.f : 1.f;
    const float z23 = z2f * z3f;
    const bool is0 = (sub == 0), is1 = (sub == 1), is2 = (sub == 2);

    // Angles in REVOLUTIONS with -0.5 half-angle folded: stored = -rad/(4*pi).
    const float REVC = -0.07957747154594767f;   // -1/(4*pi)
    const float NQPI = -0.7853981633974483f;    // -pi/4

    // ---- one-time: 16 base Rot matrices (input-constant)
    float u00r[4][4], u00i[4][4], u01r[4][4], u01i[4][4];
    const float* PP[2] = { p1, p2 };
#pragma unroll
    for (int aI = 0; aI < 2; ++aI) {
        const float* pp = PP[aI];
#pragma unroll
        for (int l = 0; l < 2; ++l) {
            const int idx = aI*2 + l;
#pragma unroll
            for (int q = 0; q < 4; ++q) {
                float phi = pp[l*12 + q*3 + 0];
                float tht = pp[l*12 + q*3 + 1];
                float omg = pp[l*12 + q*3 + 2];
                float st, ct; sincosf(0.5f*tht, &st, &ct);
                float sA, cA, sB, cB;
                sincosf(0.5f*(phi + omg), &sA, &cA);
                sincosf(0.5f*(phi - omg), &sB, &cB);
                u00r[idx][q] = rfl( cA*ct); u00i[idx][q] = rfl(-sA*ct);
                u01r[idx][q] = rfl(-cB*st); u01i[idx][q] = rfl(-sB*st);
            }
        }
    }

    // ---- per-gate scalar coefficients {dr, di, orr, oi}, z2/z3 parts folded.
    // gates 0-3: L0 q0..q3; 4-7: L1' g0..g3 (det-1, sigma on dr&oi);
    // 8-11: L2 g0..g3 (det+1, sigma on di&orr); 12-15: L3 g0..g3.
    // Chain-sign (eps0/eps1) parts applied at call sites via negation.
    float cdr[16], cdi[16], cor_[16], coi[16];
    {
        const float f0[4] = {1.f, 1.f, z2f, z3f};          // L0 sigma: n0, n1, z2, z3
#pragma unroll
        for (int q = 0; q < 4; ++q) {
            cdr[q]  = u00r[0][q];
            cdi[q]  = f0[q]*u00i[0][q];
            cor_[q] = f0[q]*u01r[0][q];
            coi[q]  = u01i[0][q];
        }
        const float f1a[4] = {z23, 1.f, z2f, z23};         // L1' sigma z-parts
#pragma unroll
        for (int q = 0; q < 4; ++q) {
            float ar = u00r[1][q] - u01r[1][q];
            float ai = u00i[1][q] + u01i[1][q];
            float br = u00r[1][q] + u01r[1][q];
            float bi = u01i[1][q] - u00i[1][q];
            cdr[4+q]  = f1a[q]*ar;
            cdi[4+q]  = ai;
            cor_[4+q] = br;
            coi[4+q]  = f1a[q]*bi;
        }
        const float f2a[4] = {z23, z2f, z3f, 1.f};         // L2 sigma z-parts
#pragma unroll
        for (int q = 0; q < 4; ++q) {
            cdr[8+q]  = u00r[2][q];
            cdi[8+q]  = f2a[q]*u00i[2][q];
            cor_[8+q] = f2a[q]*u01r[2][q];
            coi[8+q]  = u01i[2][q];
        }
        const float f3a[4] = {z23, z3f, 1.f, 1.f};         // L3 sigma z-parts
#pragma unroll
        for (int q = 0; q < 4; ++q) {
            cdr[12+q]  = u00r[3][q];
            cdi[12+q]  = f3a[q]*u00i[3][q];
            cor_[12+q] = f3a[q]*u01r[3][q];
            coi[12+q]  = u01i[3][q];
        }
    }

    // ---- KAN cubic coeffs (lane 'sub' = input dim); REVC folded.
    float kQ0[7], kQ1[7], kQ2[7], kQ3[7], kBW[7];
#pragma unroll
    for (int r = 0; r < 7; ++r) {
        float sw0 = ksw[r*16 + sub*4 + 0], sw1 = ksw[r*16 + sub*4 + 1];
        float sw2 = ksw[r*16 + sub*4 + 2], sw3 = ksw[r*16 + sub*4 + 3];
        const float f = REVC / 48.0f;
        kQ0[r] = f * (sw0 + 23.f*sw1 + 23.f*sw2 + sw3);
        kQ1[r] = f * (-3.f*sw0 - 15.f*sw1 + 15.f*sw2 + 3.f*sw3);
        kQ2[r] = f * (3.f*sw0 - 3.f*sw1 - 3.f*sw2 + 3.f*sw3);
        kQ3[r] = f * (-sw0 + 3.f*sw1 - 3.f*sw2 + sw3);
        kBW[r] = REVC * kbw[r*4 + sub];
    }
    const int pr0[3] = {0, 1, 3}, pr1[3] = {4, 2, 6};
    v2 Q0p[3], Q1p[3], Q2p[3], Q3p[3], BWp[3];
#pragma unroll
    for (int j = 0; j < 3; ++j) {
        Q0p[j] = (v2){kQ0[pr0[j]], kQ0[pr1[j]]};
        Q1p[j] = (v2){kQ1[pr0[j]], kQ1[pr1[j]]};
        Q2p[j] = (v2){kQ2[pr0[j]], kQ2[pr1[j]]};
        Q3p[j] = (v2){kQ3[pr0[j]], kQ3[pr1[j]]};
        BWp[j] = (v2){kBW[pr0[j]], kBW[pr1[j]]};
    }

    // measurement residual sign + /256 (derivation in measurement block)
    const float SCL = (is0 ? z3f : z2f) * (1.0f/256.0f);
    const float zNQ3  = z3f * NQPI;
    const float zNQ23 = z23 * NQPI;

    // ---- per-element state
    v2 H04, H12, H36;
    float H5;
    const float4* inp4 = (const float4*)inputs;
    H04 = (v2){REVC*initial_t[e*7+0], REVC*initial_t[e*7+4]};
    H12 = (v2){REVC*initial_t[e*7+1], REVC*initial_t[e*7+2]};
    H36 = (v2){REVC*initial_t[e*7+3], REVC*initial_t[e*7+6]};
    H5  = REVC*initial_t[e*7+5];
    const long BASE = (long)e * S;
    float4 XC = inp4[BASE];

    float XK = 0.f;
    v2 a00, a01, a10, a11;   // a[n0][n1]

#pragma unroll 1
    for (int t = 0; t < S; ++t) {
        const int tn = (t + 1 < S) ? t + 1 : S - 1;
        float4 XN = inp4[BASE + tn];

        // ---- fm(hidden) on |0000>: sig(a,b) = c + e1*d + e0*(w0 + e1*w1)
        {
            float c_ = z2f*H12.y;
            c_ = fmaf(z3f, H36.x, c_);
            c_ = fmaf(z23, H36.y, c_);
            float d_ = fmaf(z2f, H5, H12.x);
            float w0 = H04.x, w1 = H04.y;
            float pd = c_ + d_, qd = c_ - d_;
            float rw = w0 + w1, sw = w0 - w1;
            float s00,c00,s01,c01,s10,c10,s11,c11;
            fsincos(pd + rw, &s00, &c00);
            fsincos(qd + sw, &s01, &c01);
            fsincos(pd - rw, &s10, &c10);
            fsincos(qd - sw, &s11, &c11);
            a00 = (v2){c00, s00}; a01 = (v2){c01, s01};
            a10 = (v2){c10, s10}; a11 = (v2){c11, s11};
        }

        // ---- Phase_x trig: depends only on XC; consumer after L1' — the
        //      scheduler places it to fill slack (verified best in R7/R10 A/B).
        v2 pc00, pc01, pc10, pc11;   // {cos, sin} per chain
        {
            float hx0 = REVC*XC.x, hx1 = REVC*XC.y;
            float hx2 = REVC*XC.z, hx3 = REVC*XC.w;
            float u0 = fmaf(4.f, hx0, 1.f);
            float u1 = fmaf(4.f, hx1, 1.f);
            float u2 = fmaf(4.f, hx2, 1.f);
            float u3 = fmaf(4.f, hx3, 1.f);
            float h4r = u0*u1, h5r = u1*u2, h6r = u2*u3;
            float c2 = z2f*hx1;
            c2 = fmaf(z3f, hx2, c2);
            c2 = fmaf(zNQ23, h5r, c2);
            float d2 = fmaf(zNQ3, h6r, hx3);
            float w2 = fmaf(zNQ3, h4r, z23*hx0);
            float p2 = c2 + d2, q2v = c2 - d2;
            float ps, pc, qs, qc, rs, rc, ss_, sc;
            fsincos(p2 + w2,  &ps, &pc);
            fsincos(q2v + w2, &qs, &qc);
            fsincos(p2 - w2,  &rs, &rc);
            fsincos(q2v - w2, &ss_, &sc);
            pc00 = (v2){pc, ps}; pc01 = (v2){qc, qs};
            pc10 = (v2){rc, rs}; pc11 = (v2){sc, ss_};
        }

        // ======== L0: ansatz1 layer1 ========
        {   // q0: n0-pair; eps0 on (di,orr)
            v2 n00 = gup_s(a00, a10, cdr[0],  cdi[0],  cor_[0], coi[0]);
            v2 n10 = gup_s(a10, a00, cdr[0], -cdi[0], -cor_[0], coi[0]);
            v2 n01 = gup_s(a01, a11, cdr[0],  cdi[0],  cor_[0], coi[0]);
            v2 n11 = gup_s(a11, a01, cdr[0], -cdi[0], -cor_[0], coi[0]);
            a00=n00; a10=n10; a01=n01; a11=n11;
        }
        {   // q1: n1-pair; eps1 on (di,orr)
            v2 n00 = gup_s(a00, a01, cdr[1],  cdi[1],  cor_[1], coi[1]);
            v2 n01 = gup_s(a01, a00, cdr[1], -cdi[1], -cor_[1], coi[1]);
            v2 n10 = gup_s(a10, a11, cdr[1],  cdi[1],  cor_[1], coi[1]);
            v2 n11 = gup_s(a11, a10, cdr[1], -cdi[1], -cor_[1], coi[1]);
            a00=n00; a01=n01; a10=n10; a11=n11;
        }
        // q2: lx1 self; z2 in consts
        a00 = gup_s(a00, lx1v(a00), cdr[2], cdi[2], cor_[2], coi[2]);
        a01 = gup_s(a01, lx1v(a01), cdr[2], cdi[2], cor_[2], coi[2]);
        a10 = gup_s(a10, lx1v(a10), cdr[2], cdi[2], cor_[2], coi[2]);
        a11 = gup_s(a11, lx1v(a11), cdr[2], cdi[2], cor_[2], coi[2]);
        // q3: lx2 self; z3 in consts
        a00 = gup_s(a00, lx2v(a00), cdr[3], cdi[3], cor_[3], coi[3]);
        a01 = gup_s(a01, lx2v(a01), cdr[3], cdi[3], cor_[3], coi[3]);
        a10 = gup_s(a10, lx2v(a10), cdr[3], cdi[3], cor_[3], coi[3]);
        a11 = gup_s(a11, lx2v(a11), cdr[3], cdi[3], cor_[3], coi[3]);

        // ======== L1': H-folded ansatz1 layer2 (det -1; sigma on dr&oi) ========
        {   // g0: mask {n0,n1}: cross-pair; eps1 on (dr,oi)
            v2 n00 = gup_s(a00, a11,  cdr[4], cdi[4], cor_[4],  coi[4]);
            v2 n01 = gup_s(a01, a10, -cdr[4], cdi[4], cor_[4], -coi[4]);
            v2 n10 = gup_s(a10, a01,  cdr[4], cdi[4], cor_[4],  coi[4]);
            v2 n11 = gup_s(a11, a00, -cdr[4], cdi[4], cor_[4], -coi[4]);
            a00=n00; a01=n01; a10=n10; a11=n11;
        }
        {   // g1: mask {n1,n2}: n1-pair + lx1; eps0*eps1 on (dr,oi)
            v2 p00 = lx1v(a01), p01 = lx1v(a00), p10 = lx1v(a11), p11 = lx1v(a10);
            v2 n00 = gup_s(a00, p00,  cdr[5], cdi[5], cor_[5],  coi[5]);
            v2 n01 = gup_s(a01, p01, -cdr[5], cdi[5], cor_[5], -coi[5]);
            v2 n10 = gup_s(a10, p10, -cdr[5], cdi[5], cor_[5], -coi[5]);
            v2 n11 = gup_s(a11, p11,  cdr[5], cdi[5], cor_[5],  coi[5]);
            a00=n00; a01=n01; a10=n10; a11=n11;
        }
        // g2: mask {n2,n3}: x3 self; eps0*eps1 on (dr,oi)
        a00 = gup_s(a00, x3v(a00),  cdr[6], cdi[6], cor_[6],  coi[6]);
        a01 = gup_s(a01, x3v(a01), -cdr[6], cdi[6], cor_[6], -coi[6]);
        a10 = gup_s(a10, x3v(a10), -cdr[6], cdi[6], cor_[6], -coi[6]);
        a11 = gup_s(a11, x3v(a11),  cdr[6], cdi[6], cor_[6],  coi[6]);
        {   // g3: mask {n0,n1,n3}: cross-pair + lx2; eps0*eps1 on (dr,oi)
            v2 p00 = lx2v(a11), p01 = lx2v(a10), p10 = lx2v(a01), p11 = lx2v(a00);
            v2 n00 = gup_s(a00, p00,  cdr[7], cdi[7], cor_[7],  coi[7]);
            v2 n01 = gup_s(a01, p01, -cdr[7], cdi[7], cor_[7], -coi[7]);
            v2 n10 = gup_s(a10, p10, -cdr[7], cdi[7], cor_[7], -coi[7]);
            v2 n11 = gup_s(a11, p11,  cdr[7], cdi[7], cor_[7],  coi[7]);
            a00=n00; a01=n01; a10=n10; a11=n11;
        }

        // ======== Phase_x apply ========
        a00 = prot(a00, pc00);
        a01 = prot(a01, pc01);
        a10 = prot(a10, pc10);
        a11 = prot(a11, pc11);

        // ======== L2: ansatz2 layer1 (det +1; sigma on di&orr) ========
        {   // g0: mask {n0}: n0-pair; eps0 on (di,orr)
            v2 n00 = gup_s(a00, a10, cdr[8],  cdi[8],  cor_[8], coi[8]);
            v2 n10 = gup_s(a10, a00, cdr[8], -cdi[8], -cor_[8], coi[8]);
            v2 n01 = gup_s(a01, a11, cdr[8],  cdi[8],  cor_[8], coi[8]);
            v2 n11 = gup_s(a11, a01, cdr[8], -cdi[8], -cor_[8], coi[8]);
            a00=n00; a10=n10; a01=n01; a11=n11;
        }
        {   // g1: mask {n0,n2}: n0-pair + lx1; no chain signs (z2 in consts)
            v2 p00 = lx1v(a10), p10 = lx1v(a00), p01 = lx1v(a11), p11 = lx1v(a01);
            v2 n00 = gup_s(a00, p00, cdr[9], cdi[9], cor_[9], coi[9]);
            v2 n10 = gup_s(a10, p10, cdr[9], cdi[9], cor_[9], coi[9]);
            v2 n01 = gup_s(a01, p01, cdr[9], cdi[9], cor_[9], coi[9]);
            v2 n11 = gup_s(a11, p11, cdr[9], cdi[9], cor_[9], coi[9]);
            a00=n00; a10=n10; a01=n01; a11=n11;
        }
        {   // g2: mask {n0,n3}: n0-pair + lx2; no chain signs (z3 in consts)
            v2 p00 = lx2v(a10), p10 = lx2v(a00), p01 = lx2v(a11), p11 = lx2v(a01);
            v2 n00 = gup_s(a00, p00, cdr[10], cdi[10], cor_[10], coi[10]);
            v2 n10 = gup_s(a10, p10, cdr[10], cdi[10], cor_[10], coi[10]);
            v2 n01 = gup_s(a01, p01, cdr[10], cdi[10], cor_[10], coi[10]);
            v2 n11 = gup_s(a11, p11, cdr[10], cdi[10], cor_[10], coi[10]);
            a00=n00; a10=n10; a01=n01; a11=n11;
        }
        {   // g3: mask {n1}: n1-pair; eps1 on (di,orr)
            v2 n00 = gup_s(a00, a01, cdr[11],  cdi[11],  cor_[11], coi[11]);
            v2 n01 = gup_s(a01, a00, cdr[11], -cdi[11], -cor_[11], coi[11]);
            v2 n10 = gup_s(a10, a11, cdr[11],  cdi[11],  cor_[11], coi[11]);
            v2 n11 = gup_s(a11, a10, cdr[11], -cdi[11], -cor_[11], coi[11]);
            a00=n00; a01=n01; a10=n10; a11=n11;
        }

        // ======== L3: ansatz2 layer2 (det +1; sigma on di&orr) ========
        // g0: mask {n2}: lx1 self; eps1 on (di,orr), z23 in consts
        a00 = gup_s(a00, lx1v(a00), cdr[12],  cdi[12],  cor_[12], coi[12]);
        a01 = gup_s(a01, lx1v(a01), cdr[12], -cdi[12], -cor_[12], coi[12]);
        a10 = gup_s(a10, lx1v(a10), cdr[12],  cdi[12],  cor_[12], coi[12]);
        a11 = gup_s(a11, lx1v(a11), cdr[12], -cdi[12], -cor_[12], coi[12]);
        // g1: mask {n2,n3}: x3 self; eps0 on (di,orr), z3 in consts
        a00 = gup_s(a00, x3v(a00), cdr[13],  cdi[13],  cor_[13], coi[13]);
        a01 = gup_s(a01, x3v(a01), cdr[13],  cdi[13],  cor_[13], coi[13]);
        a10 = gup_s(a10, x3v(a10), cdr[13], -cdi[13], -cor_[13], coi[13]);
        a11 = gup_s(a11, x3v(a11), cdr[13], -cdi[13], -cor_[13], coi[13]);
        {   // g2: mask {n0,n1,n3}: cross-pair + lx2; eps0 on (di,orr)
            v2 p00 = lx2v(a11), p01 = lx2v(a10), p10 = lx2v(a01), p11 = lx2v(a00);
            v2 n00 = gup_s(a00, p00, cdr[14],  cdi[14],  cor_[14], coi[14]);
            v2 n01 = gup_s(a01, p01, cdr[14],  cdi[14],  cor_[14], coi[14]);
            v2 n10 = gup_s(a10, p10, cdr[14], -cdi[14], -cor_[14], coi[14]);
            v2 n11 = gup_s(a11, p11, cdr[14], -cdi[14], -cor_[14], coi[14]);
            a00=n00; a01=n01; a10=n10; a11=n11;
        }
        {   // g3: mask {n1,n2}: n1-pair + lx1; eps0*eps1 on (di,orr)
            v2 p00 = lx1v(a01), p01 = lx1v(a00), p10 = lx1v(a11), p11 = lx1v(a10);
            v2 n00 = gup_s(a00, p00, cdr[15],  cdi[15],  cor_[15], coi[15]);
            v2 n01 = gup_s(a01, p01, cdr[15], -cdi[15], -cor_[15], coi[15]);
            v2 n10 = gup_s(a10, p10, cdr[15], -cdi[15], -cor_[15], coi[15]);
            v2 n11 = gup_s(a11, p11, cdr[15],  cdi[15],  cor_[15], coi[15]);
            a00=n00; a01=n01; a10=n10; a11=n11;
        }

        // ---- measurement (Walsh over n0,n1 in-register; n2,n3 quad DPP)
        // EV0 = sum(-1)^{n0+n1+n3}p, EV1 = sum(-1)^{n0+n1+n2}p,
        // EV2 = sum(-1)^{n1+n2}p,    EV3 = sum(-1)^{n0+n2}p   (probs x256)
        {
            float m00 = fmaf(a00.y, a00.y, a00.x*a00.x);
            float m01 = fmaf(a01.y, a01.y, a01.x*a01.x);
            float m10 = fmaf(a10.y, a10.y, a10.x*a10.x);
            float m11 = fmaf(a11.y, a11.y, a11.x*a11.x);
            float g_ = m00 - m01, h_ = m10 - m11;
            float dl01 = g_ - h_;                         // (-1)^{n0^n1}
            float sn1  = g_ + h_;                         // (-1)^{n1}
            float dn0  = (m00 + m01) - (m10 + m11);       // (-1)^{n0}
            float l1a = lx1(dl01);
            float up = dl01 + l1a;
            float um = dl01 - l1a;
            float t0 = up - lx2(up);                      // z3f * EV0*256
            float t1 = um + lx2(um);                      // z2f * EV1*256
            float vm = sn1 - lx1(sn1);
            float t2 = vm + lx2(vm);                      // z2f * EV2*256
            float wm = dn0 - lx1(dn0);
            float t3 = wm + lx2(wm);                      // z2f * EV3*256
            float pre = is0 ? t0 : (is1 ? t1 : (is2 ? t2 : t3));
            XK = pre * SCL;
        }

        // ---- KAN (packed pairs): lane sub = input dim; quad-reduce sums dims
        {
            float xk = XK;
            float eneg = __builtin_amdgcn_exp2f(xk * -1.44269504088896f);
            float silu = xk * __builtin_amdgcn_rcpf(1.0f + eneg);
            v2 xs = (v2){xk, xk}, ss = (v2){silu, silu};
            v2 op[3];
#pragma unroll
            for (int k = 0; k < 3; ++k) {
                v2 o = __builtin_elementwise_fma(Q3p[k], xs, Q2p[k]);
                o = __builtin_elementwise_fma(o, xs, Q1p[k]);
                o = __builtin_elementwise_fma(o, xs, Q0p[k]);
                o = __builtin_elementwise_fma(BWp[k], ss, o);
                o = o + (v2){lx1(o.x), lx1(o.y)};
                o = o + (v2){lx2(o.x), lx2(o.y)};
                op[k] = o;
            }
            {   // scalar r=5
                float o = fmaf(kQ3[5], xk, kQ2[5]);
                o = fmaf(o, xk, kQ1[5]);
                o = fmaf(o, xk, kQ0[5]);
                o = fmaf(kBW[5], silu, o);
                o += lx1(o); o += lx2(o);
                H5 = o;
            }
            H04 = op[0]; H12 = op[1]; H36 = op[2];
            XC = XN;
        }
    }

    // ---- classifier head: quad lanes hold ev0..ev3 per element
    {
        float xk  = XK;
        float ev1 = qperm<0x55>(xk);
        float ev2 = qperm<0xAA>(xk);
        float ev3 = qperm<0xFF>(xk);
        if (is0) {
            float acc = cb2[0];
#pragma unroll
            for (int i = 0; i < 16; ++i) {
                float h = cb1[i] + w1[i*4+0]*xk + w1[i*4+1]*ev1
                        + w1[i*4+2]*ev2 + w1[i*4+3]*ev3;
                h = fmaxf(h, 0.0f);
                acc += w2[i]*h;
            }
            out[e] = acc;
        }
    }
}

extern "C" void kernel_launch(void* const* d_in, const int* in_sizes, int n_in,
                              void* d_out, int out_size, void* d_ws, size_t ws_size,
                              hipStream_t stream) {
    const float* inputs    = (const float*)d_in[0];
    const float* initial_t = (const float*)d_in[1];
    const float* p1        = (const float*)d_in[2];
    const float* p2        = (const float*)d_in[3];
    const float* kbw       = (const float*)d_in[4];
    const float* ksw       = (const float*)d_in[5];
    const float* w1        = (const float*)d_in[6];
    const float* cb1       = (const float*)d_in[7];
    const float* w2        = (const float*)d_in[8];
    const float* cb2       = (const float*)d_in[9];

    const int B = in_sizes[1] / 7;            // 16384
    const int S = in_sizes[0] / (B * 4);      // 256

    const int threads = B * 4;                // 4 lanes/element, 1 element/thread
    const int block = 256;
    const int grid = (threads + block - 1) / block;   // 256 blocks -> 1 wave/SIMD

    qrnn_kernel<<<grid, block, 0, stream>>>(inputs, initial_t, p1, p2, kbw, ksw,
                                            w1, cb1, w2, cb2, (float*)d_out, B, S);
}